// Round 16
// baseline (262.896 us; speedup 1.0000x reference)
//
#include <hip/hip_runtime.h>
#include <hip/hip_bf16.h>

#define NTHREADS 256
#define CAP 6144          // per-partition edge capacity (mean 4096 -> huge margin)
#define P1_EDGES 8192     // edges per pass1 block

typedef unsigned int uint32;

// accumulate 8 bf16 feats (packed in uint4), scaled by w, into two float4 accs
__device__ __forceinline__ void fma8(float4& A0, float4& A1, uint4 v, float w) {
    A0.x += __uint_as_float(v.x << 16) * w;
    A0.y += __uint_as_float(v.x & 0xffff0000u) * w;
    A0.z += __uint_as_float(v.y << 16) * w;
    A0.w += __uint_as_float(v.y & 0xffff0000u) * w;
    A1.x += __uint_as_float(v.z << 16) * w;
    A1.y += __uint_as_float(v.z & 0xffff0000u) * w;
    A1.z += __uint_as_float(v.w << 16) * w;
    A1.w += __uint_as_float(v.w & 0xffff0000u) * w;
}
__device__ __forceinline__ void acc8(float4& A0, float4& A1, uint4 v) {
    A0.x += __uint_as_float(v.x << 16);
    A0.y += __uint_as_float(v.x & 0xffff0000u);
    A0.z += __uint_as_float(v.y << 16);
    A0.w += __uint_as_float(v.y & 0xffff0000u);
    A1.x += __uint_as_float(v.z << 16);
    A1.y += __uint_as_float(v.z & 0xffff0000u);
    A1.z += __uint_as_float(v.w << 16);
    A1.w += __uint_as_float(v.w & 0xffff0000u);
}

// ---------------- W staging: f32 LDS tile ----------------
__device__ __forceinline__ void stage_W(const float* __restrict__ W, float* sW) {
    int t = threadIdx.x;
    const float4* W4 = (const float4*)W;
    float4* sW4 = (float4*)sW;
#pragma unroll
    for (int i = 0; i < 4; i++) sW4[t + NTHREADS * i] = W4[t + NTHREADS * i];
}

// ---------------- GEMM compute phase: acc over sX (f32) x sW (f32) ----------------
// Row targets: sP (LDS-staged permuted node ids) or identity (sP==nullptr).
__device__ __forceinline__ void gemm_compute(
    const float* __restrict__ sW, const float* __restrict__ sX,
    const float* __restrict__ sD, const int* __restrict__ sP,
    __hip_bfloat16* __restrict__ out, int n_rows, int row_base) {
    int t = threadIdx.x;
    int c = t & 63;
    int r0 = t >> 6;
    float acc[16];
#pragma unroll
    for (int j = 0; j < 16; j++) acc[j] = 0.f;

    for (int k = 0; k < 64; k += 4) {
        float w0 = sW[(k + 0) * 64 + c];
        float w1 = sW[(k + 1) * 64 + c];
        float w2 = sW[(k + 2) * 64 + c];
        float w3 = sW[(k + 3) * 64 + c];
#pragma unroll
        for (int j = 0; j < 16; j++) {
            float4 xv = *(const float4*)(sX + (r0 + 4 * j) * 64 + k);
            acc[j] += xv.x * w0 + xv.y * w1 + xv.z * w2 + xv.w * w3;
        }
    }

#pragma unroll
    for (int j = 0; j < 16; j++) {
        int rr = r0 + 4 * j;
        int r = row_base + rr;
        if (r < n_rows) {
            float s = sD ? sD[rr] : 1.0f;
            int nd = sP ? sP[rr] : r;
            out[(size_t)nd * 64 + c] = __float2bfloat16(s * acc[j]);
        }
    }
}

// ---------------- pass1 (edge partition scatter) fused with layer-0 GEMM ----------------
__global__ __launch_bounds__(NTHREADS) void pass1_gemm0(
    const int* __restrict__ ei, int nE, int* gcur, uint32* __restrict__ pbuf, int npart,
    const float* __restrict__ x, __hip_bfloat16* __restrict__ U,
    const float* __restrict__ W, int n_rows, int nP1) {
    __shared__ __align__(16) float sW[64 * 64];
    __shared__ __align__(16) float sX[64 * 64];

    int bid = blockIdx.x;
    int t = threadIdx.x;

    if (bid < nP1) {
        int* hist = (int*)sW;            // [npart]
        int* base = hist + npart;        // [npart]
        int* cnt  = base + npart;        // [npart]
        for (int i = t; i < npart; i += NTHREADS) { hist[i] = 0; cnt[i] = 0; }
        __syncthreads();

        int e0 = bid * P1_EDGES;
#pragma unroll 4
        for (int j = 0; j < P1_EDGES / NTHREADS; j++) {
            int e = e0 + j * NTHREADS + t;
            if (e < nE) atomicAdd(&hist[ei[nE + e] >> 8], 1);
        }
        __syncthreads();
        for (int i = t; i < npart; i += NTHREADS) {
            base[i] = hist[i] ? atomicAdd(&gcur[i * 16], hist[i]) : 0;
        }
        __syncthreads();
#pragma unroll 4
        for (int j = 0; j < P1_EDGES / NTHREADS; j++) {
            int e = e0 + j * NTHREADS + t;
            if (e < nE) {
                int s = ei[e];
                int d = ei[nE + e];
                int p = d >> 8;
                int off = atomicAdd(&cnt[p], 1);
                int pos = base[p] + off;
                if (pos < CAP) pbuf[(size_t)p * CAP + pos] = ((uint32)s << 8) | (uint32)(d & 255);
            }
        }
        return;
    }

    int row_base = (bid - nP1) * 64;
    stage_W(W, sW);
    float4* sX4 = (float4*)sX;
#pragma unroll
    for (int i = 0; i < 4; i++) {
        int idx = t + NTHREADS * i;
        int r = row_base + (idx >> 4);
        float4 v = make_float4(0.f, 0.f, 0.f, 0.f);
        if (r < n_rows) v = ((const float4*)(x + (size_t)r * 64))[idx & 15];
        sX4[idx] = v;
    }
    __syncthreads();
    gemm_compute(sW, sX, nullptr, nullptr, U, n_rows, row_base);
}

// ---------------- scan over partition totals -> pbase (exclusive); row_ptr[N]=E ----------------
__global__ __launch_bounds__(512) void scanP(const int* __restrict__ gcur, int* pbase,
                                             int npart, int n, int nE, int* row_ptr) {
    __shared__ int sm[512];
    int t = threadIdx.x;
    int v = (t < npart) ? gcur[t * 16] : 0;
    sm[t] = v;
    __syncthreads();
    for (int off = 1; off < 512; off <<= 1) {
        int a = (t >= off) ? sm[t - off] : 0;
        __syncthreads();
        sm[t] += a;
        __syncthreads();
    }
    if (t < npart) pbase[t] = sm[t] - v;
    if (t == 0) row_ptr[n] = nE;
}

// ---------------- pass2: per-partition CSR finish + degree-key histogram ----------------
__global__ __launch_bounds__(NTHREADS) void pass2(
    const uint32* __restrict__ pbuf, const int* __restrict__ gcur,
    const int* __restrict__ pbase, int* __restrict__ row_ptr,
    float* __restrict__ dis, int* __restrict__ col,
    int* __restrict__ keyarr, int* __restrict__ dhist_g, int n) {
    __shared__ int hist[256];
    __shared__ int excl[256];
    __shared__ int cnt[256];
    __shared__ int sm[256];
    __shared__ int ldh[256];

    int p = blockIdx.x;
    int t = threadIdx.x;
    hist[t] = 0;
    cnt[t] = 0;
    ldh[t] = 0;
    __syncthreads();

    int total = gcur[p * 16];
    if (total > CAP) total = CAP;
    const uint32* pb = pbuf + (size_t)p * CAP;

    for (int i = t; i < total; i += NTHREADS) atomicAdd(&hist[pb[i] & 255], 1);
    __syncthreads();

    sm[t] = hist[t];
    __syncthreads();
    for (int off = 1; off < 256; off <<= 1) {
        int a = (t >= off) ? sm[t - off] : 0;
        __syncthreads();
        sm[t] += a;
        __syncthreads();
    }
    excl[t] = sm[t] - hist[t];
    __syncthreads();

    int rbase = pbase[p];
    int node = p * 256 + t;
    if (node < n) {
        int deg = hist[t];
        row_ptr[node] = rbase + excl[t];
        dis[node] = rsqrtf(1.0f + (float)deg);
        int key = 255 - (deg > 255 ? 255 : deg);   // descending degree
        keyarr[node] = key;
        atomicAdd(&ldh[key], 1);                   // LDS first (avoid hot global address)
    }
    __syncthreads();
    if (ldh[t]) atomicAdd(&dhist_g[t], ldh[t]);    // one global add per (block,key)

    for (int i = t; i < total; i += NTHREADS) {
        uint32 v = pb[i];
        int dl = v & 255;
        int off = atomicAdd(&cnt[dl], 1);
        col[rbase + excl[dl] + off] = (int)(v >> 8);
    }
}

// ---------------- scanK: exclusive scan of 256 degree-key counts (in place) ----------------
__global__ __launch_bounds__(256) void scanK(int* dhist) {
    __shared__ int sm[256];
    int t = threadIdx.x;
    int v = dhist[t];
    sm[t] = v;
    __syncthreads();
    for (int off = 1; off < 256; off <<= 1) {
        int a = (t >= off) ? sm[t - off] : 0;
        __syncthreads();
        sm[t] += a;
        __syncthreads();
    }
    dhist[t] = sm[t] - v;   // becomes cursor base for permK
}

// ---------------- permK: counting-sort scatter -> perm (heavy degrees first) ----------------
__global__ __launch_bounds__(256) void permK(const int* __restrict__ keyarr,
                                             int* dcur, int* __restrict__ perm, int n) {
    __shared__ int lh[256];
    __shared__ int lbase[256];
    __shared__ int lcnt[256];
    int t = threadIdx.x;
    lh[t] = 0;
    lcnt[t] = 0;
    __syncthreads();
    int i = blockIdx.x * 256 + t;
    int key = (i < n) ? keyarr[i] : -1;
    if (key >= 0) atomicAdd(&lh[key], 1);
    __syncthreads();
    if (lh[t]) lbase[t] = atomicAdd(&dcur[t], lh[t]);
    __syncthreads();
    if (key >= 0) {
        int off = atomicAdd(&lcnt[key], 1);
        perm[lbase[key] + off] = i;
    }
}

// ---------------- gather one node's aggregated+activated row into LDS ----------------
template <bool WEIGHTED>
__device__ __forceinline__ void gather_row(
    const uint4* __restrict__ T8, const float* __restrict__ dis,
    const float* __restrict__ bias,
    const int* __restrict__ row_ptr, const int* __restrict__ col,
    int node, int q, float* __restrict__ sXrow) {
    float4 o0, o1;
    if (node >= 0) {
        float dn = dis[node];
        float4 a0 = make_float4(0.f, 0.f, 0.f, 0.f);
        float4 a1 = make_float4(0.f, 0.f, 0.f, 0.f);
        {
            uint4 sv = T8[(size_t)node * 8 + q];
            if (WEIGHTED) fma8(a0, a1, sv, dn);
            else          acc8(a0, a1, sv);
        }
        int e0 = row_ptr[node];
        int e1 = row_ptr[node + 1];
        int e = e0;
        for (; e + 7 < e1; e += 8) {
            int s0 = col[e],     s1 = col[e + 1], s2 = col[e + 2], s3 = col[e + 3];
            int s4 = col[e + 4], s5 = col[e + 5], s6 = col[e + 6], s7 = col[e + 7];
            uint4 v0 = T8[(size_t)s0 * 8 + q];
            uint4 v1 = T8[(size_t)s1 * 8 + q];
            uint4 v2 = T8[(size_t)s2 * 8 + q];
            uint4 v3 = T8[(size_t)s3 * 8 + q];
            uint4 v4 = T8[(size_t)s4 * 8 + q];
            uint4 v5 = T8[(size_t)s5 * 8 + q];
            uint4 v6 = T8[(size_t)s6 * 8 + q];
            uint4 v7 = T8[(size_t)s7 * 8 + q];
            if (WEIGHTED) {
                fma8(a0, a1, v0, dis[s0]); fma8(a0, a1, v1, dis[s1]);
                fma8(a0, a1, v2, dis[s2]); fma8(a0, a1, v3, dis[s3]);
                fma8(a0, a1, v4, dis[s4]); fma8(a0, a1, v5, dis[s5]);
                fma8(a0, a1, v6, dis[s6]); fma8(a0, a1, v7, dis[s7]);
            } else {
                acc8(a0, a1, v0); acc8(a0, a1, v1); acc8(a0, a1, v2); acc8(a0, a1, v3);
                acc8(a0, a1, v4); acc8(a0, a1, v5); acc8(a0, a1, v6); acc8(a0, a1, v7);
            }
        }
        for (; e + 3 < e1; e += 4) {
            int s0 = col[e], s1 = col[e + 1], s2 = col[e + 2], s3 = col[e + 3];
            uint4 v0 = T8[(size_t)s0 * 8 + q];
            uint4 v1 = T8[(size_t)s1 * 8 + q];
            uint4 v2 = T8[(size_t)s2 * 8 + q];
            uint4 v3 = T8[(size_t)s3 * 8 + q];
            if (WEIGHTED) {
                fma8(a0, a1, v0, dis[s0]); fma8(a0, a1, v1, dis[s1]);
                fma8(a0, a1, v2, dis[s2]); fma8(a0, a1, v3, dis[s3]);
            } else {
                acc8(a0, a1, v0); acc8(a0, a1, v1); acc8(a0, a1, v2); acc8(a0, a1, v3);
            }
        }
        for (; e < e1; e++) {
            int s0 = col[e];
            uint4 v0 = T8[(size_t)s0 * 8 + q];
            if (WEIGHTED) fma8(a0, a1, v0, dis[s0]);
            else          acc8(a0, a1, v0);
        }
        float4 b0 = ((const float4*)bias)[q * 2];
        float4 b1 = ((const float4*)bias)[q * 2 + 1];
        o0.x = fmaxf(b0.x + dn * a0.x, 0.f);
        o0.y = fmaxf(b0.y + dn * a0.y, 0.f);
        o0.z = fmaxf(b0.z + dn * a0.z, 0.f);
        o0.w = fmaxf(b0.w + dn * a0.w, 0.f);
        o1.x = fmaxf(b1.x + dn * a1.x, 0.f);
        o1.y = fmaxf(b1.y + dn * a1.y, 0.f);
        o1.z = fmaxf(b1.z + dn * a1.z, 0.f);
        o1.w = fmaxf(b1.w + dn * a1.w, 0.f);
    } else {
        o0 = make_float4(0.f, 0.f, 0.f, 0.f);
        o1 = o0;
    }
    ((float4*)sXrow)[q * 2] = o0;
    ((float4*)sXrow)[q * 2 + 1] = o1;
}

// ---------------- fused aggregate(layer l) + GEMM(layer l+1), degree-sorted nodes ----------------
template <bool WEIGHTED>
__global__ __launch_bounds__(NTHREADS) void agg_gemm(
    const __hip_bfloat16* __restrict__ Tin, __hip_bfloat16* __restrict__ Tout,
    const float* __restrict__ W, const float* __restrict__ dis,
    const float* __restrict__ bias,
    const int* __restrict__ row_ptr, const int* __restrict__ col,
    const int* __restrict__ perm, int n) {
    __shared__ __align__(16) float sW[64 * 64];
    __shared__ __align__(16) float sX[64 * 64];
    __shared__ float sD[64];
    __shared__ int sP[64];
    int t = threadIdx.x;
    int row_base = blockIdx.x * 64;

    stage_W(W, sW);
    if (t < 64) {
        int idx = row_base + t;
        int nd = (idx < n) ? perm[idx] : -1;
        sP[t] = nd;
        sD[t] = (nd >= 0) ? dis[nd] : 0.f;
    }

    const uint4* T8 = (const uint4*)Tin;
    int q = t & 7;
    int l = t >> 3;  // 0..31
    int i1 = row_base + l;
    int i2 = row_base + 32 + l;
    int nd1 = (i1 < n) ? perm[i1] : -1;
    int nd2 = (i2 < n) ? perm[i2] : -1;
    gather_row<WEIGHTED>(T8, dis, bias, row_ptr, col, nd1, q, sX + l * 64);
    gather_row<WEIGHTED>(T8, dis, bias, row_ptr, col, nd2, q, sX + (32 + l) * 64);
    __syncthreads();

    gemm_compute(sW, sX, sD, sP, Tout, n, row_base);
}

// ---------------- fused aggregate(layer 2) + sum-pool (degree-sorted nodes) ----------------
__global__ __launch_bounds__(NTHREADS) void agg_pool(
    const __hip_bfloat16* __restrict__ Tin,
    const float* __restrict__ dis, const float* __restrict__ bias,
    const int* __restrict__ row_ptr, const int* __restrict__ col,
    const int* __restrict__ gid, const int* __restrict__ perm,
    float* __restrict__ pooled, int n) {
    __shared__ __align__(16) float sX[64 * 64];
    __shared__ int sG[64];
    int t = threadIdx.x;
    int row_base = blockIdx.x * 64;

    if (t < 64) {
        int idx = row_base + t;
        int nd = (idx < n) ? perm[idx] : -1;
        sG[t] = (nd >= 0) ? gid[nd] : -1;
    }

    const uint4* T8 = (const uint4*)Tin;
    int q = t & 7;
    int l = t >> 3;
    int i1 = row_base + l;
    int i2 = row_base + 32 + l;
    int nd1 = (i1 < n) ? perm[i1] : -1;
    int nd2 = (i2 < n) ? perm[i2] : -1;
    gather_row<false>(T8, dis, bias, row_ptr, col, nd1, q, sX + l * 64);
    gather_row<false>(T8, dis, bias, row_ptr, col, nd2, q, sX + (32 + l) * 64);
    __syncthreads();

    // rows now have random gids (permuted) -> run-length rarely fires; accumulate & flush
    int f = t & 63;
    int w = t >> 6;
    float racc = 0.f;
    int cur = -1;
#pragma unroll
    for (int i = 0; i < 16; i++) {
        int r = i * 4 + w;
        int g = sG[r];
        if (g != cur) {
            if (cur >= 0 && racc != 0.f) atomicAdd(&pooled[cur * 64 + f], racc);
            racc = 0.f;
            cur = g;
        }
        if (g >= 0) racc += sX[r * 64 + f];
    }
    if (cur >= 0 && racc != 0.f) atomicAdd(&pooled[cur * 64 + f], racc);
}

// ---------------- head MLP (one block) ----------------
__global__ __launch_bounds__(NTHREADS) void head_kernel(
    const float* __restrict__ pooled, const float* __restrict__ gf,
    const float* __restrict__ glob_w, const float* __restrict__ glob_b,
    const float* __restrict__ lin1_w, const float* __restrict__ lin1_b,
    const float* __restrict__ lin2_w, const float* __restrict__ lin2_b,
    const float* __restrict__ lin3_w, const float* __restrict__ lin3_b,
    const float* __restrict__ lin4_w, const float* __restrict__ lin4_b,
    float* __restrict__ out) {
    __shared__ float gx[64 * 32];
    __shared__ float zA[64 * 64];
    __shared__ float zB[64 * 64];
    int t = threadIdx.x;

    for (int i = t; i < 64 * 32; i += NTHREADS) {
        int g = i >> 5, j = i & 31;
        float acc = glob_b[j];
        for (int k = 0; k < 32; k++) acc += gf[g * 32 + k] * glob_w[k * 32 + j];
        gx[i] = fmaxf(acc, 0.f);
    }
    for (int i = t; i < 4096; i += NTHREADS) {
        int g = i >> 6, j = i & 63;
        float acc = lin1_b[j];
        for (int k = 0; k < 64; k++) acc += pooled[g * 64 + k] * lin1_w[k * 64 + j];
        zA[i] = fmaxf(acc, 0.f);
    }
    __syncthreads();
    for (int i = t; i < 4096; i += NTHREADS) {
        int g = i >> 6, j = i & 63;
        float acc = lin2_b[j];
        for (int k = 0; k < 64; k++) acc += zA[g * 64 + k] * lin2_w[k * 64 + j];
        for (int k = 0; k < 32; k++) acc += gx[g * 32 + k] * lin2_w[(64 + k) * 64 + j];
        zB[i] = fmaxf(acc, 0.f);
    }
    __syncthreads();
    for (int i = t; i < 4096; i += NTHREADS) {
        int g = i >> 6, j = i & 63;
        float acc = lin3_b[j];
        for (int k = 0; k < 64; k++) acc += zB[g * 64 + k] * lin3_w[k * 64 + j];
        zA[i] = fmaxf(acc, 0.f);
    }
    __syncthreads();
    if (t < 64) {
        float acc = lin4_b[0];
        for (int k = 0; k < 64; k++) acc += zA[t * 64 + k] * lin4_w[k];
        out[t] = acc;
    }
}

extern "C" void kernel_launch(void* const* d_in, const int* in_sizes, int n_in,
                              void* d_out, int out_size, void* d_ws, size_t ws_size,
                              hipStream_t stream) {
    const float* x      = (const float*)d_in[0];
    const float* gf     = (const float*)d_in[1];
    const float* conv_w[3] = {(const float*)d_in[2], (const float*)d_in[4], (const float*)d_in[6]};
    const float* conv_b[3] = {(const float*)d_in[3], (const float*)d_in[5], (const float*)d_in[7]};
    const float* lin1_w = (const float*)d_in[8];
    const float* lin1_b = (const float*)d_in[9];
    const float* glob_w = (const float*)d_in[10];
    const float* glob_b = (const float*)d_in[11];
    const float* lin2_w = (const float*)d_in[12];
    const float* lin2_b = (const float*)d_in[13];
    const float* lin3_w = (const float*)d_in[14];
    const float* lin3_b = (const float*)d_in[15];
    const float* lin4_w = (const float*)d_in[16];
    const float* lin4_b = (const float*)d_in[17];
    const int* ei  = (const int*)d_in[18];
    const int* gid = (const int*)d_in[19];

    const int N = in_sizes[0] / 64;   // 100000
    const int E = in_sizes[18] / 2;   // 1600000
    const int NPART = (N + 255) >> 8; // 391

    // workspace layout (16B-aligned segments)
    char* ws = (char*)d_ws;
    float* dis     = (float*)ws;                 ws += (size_t)N * 4;
    float* pooled  = (float*)ws;                 ws += 4096 * 4;
    __hip_bfloat16* U  = (__hip_bfloat16*)ws;    ws += (size_t)N * 64 * 2;  // layer0 out / layer2 in
    __hip_bfloat16* T1 = (__hip_bfloat16*)ws;    ws += (size_t)N * 64 * 2;  // layer1 out
    int*   row_ptr = (int*)ws;                   ws += ((size_t)N + 4) * 4;
    int*   col     = (int*)ws;                   ws += (size_t)E * 4;
    uint32* pbuf   = (uint32*)ws;                ws += (size_t)NPART * CAP * 4;
    int*   gcur    = (int*)ws;                   ws += (size_t)NPART * 16 * 4;
    int*   pbase   = (int*)ws;                   ws += (size_t)((NPART + 15) & ~15) * 4;
    int*   keyarr  = (int*)ws;                   ws += (size_t)N * 4;
    int*   dhist   = (int*)ws;                   ws += 256 * 4;
    int*   perm    = (int*)ws;                   ws += (size_t)N * 4;

    const int nP1 = (E + P1_EDGES - 1) / P1_EDGES;   // 196
    const int gemm_blocks = (N + 63) / 64;           // 1563
    const int nb_N = (N + 255) / 256;

    // ---- CSR build pass1 (partition scatter) fused with unscaled layer-0 GEMM ----
    hipMemsetAsync(gcur, 0, (size_t)NPART * 16 * 4, stream);
    hipMemsetAsync(pooled, 0, 4096 * 4, stream);
    hipMemsetAsync(dhist, 0, 256 * 4, stream);
    pass1_gemm0<<<nP1 + gemm_blocks, NTHREADS, 0, stream>>>(
        ei, E, gcur, pbuf, NPART, x, U, conv_w[0], N, nP1);

    // ---- partition-total scan + per-partition CSR finish (+ degree keys) ----
    scanP<<<1, 512, 0, stream>>>(gcur, pbase, NPART, N, E, row_ptr);
    pass2<<<NPART, NTHREADS, 0, stream>>>(pbuf, gcur, pbase, row_ptr, dis, col,
                                          keyarr, dhist, N);

    // ---- degree-descending permutation (counting sort) ----
    scanK<<<1, 256, 0, stream>>>(dhist);
    permK<<<nb_N, 256, 0, stream>>>(keyarr, dhist, perm, N);

    // agg(layer0, weighted) + gemm(layer1): U -> T1 (prescaled)
    agg_gemm<true><<<gemm_blocks, NTHREADS, 0, stream>>>(
        U, T1, conv_w[1], dis, conv_b[0], row_ptr, col, perm, N);

    // agg(layer1) + gemm(layer2): T1 -> U (prescaled, reused buffer)
    agg_gemm<false><<<gemm_blocks, NTHREADS, 0, stream>>>(
        T1, U, conv_w[2], dis, conv_b[1], row_ptr, col, perm, N);

    // agg(layer2) + relu + pool: U -> pooled
    agg_pool<<<gemm_blocks, NTHREADS, 0, stream>>>(
        U, dis, conv_b[2], row_ptr, col, gid, perm, pooled, N);

    // head MLP
    head_kernel<<<1, NTHREADS, 0, stream>>>(pooled, gf,
                                            glob_w, glob_b, lin1_w, lin1_b,
                                            lin2_w, lin2_b, lin3_w, lin3_b,
                                            lin4_w, lin4_b, (float*)d_out);
}

// Round 17
// 213.948 us; speedup vs baseline: 1.2288x; 1.2288x over previous
//
#include <hip/hip_runtime.h>
#include <hip/hip_bf16.h>

#define NTHREADS 256
#define CAP 6144          // per-partition edge capacity (mean 4096 -> huge margin)
#define P1_EDGES 8192     // edges per pass1 block

typedef unsigned int uint32;

// accumulate 8 bf16 feats (packed in uint4), scaled by w, into two float4 accs
__device__ __forceinline__ void fma8(float4& A0, float4& A1, uint4 v, float w) {
    A0.x += __uint_as_float(v.x << 16) * w;
    A0.y += __uint_as_float(v.x & 0xffff0000u) * w;
    A0.z += __uint_as_float(v.y << 16) * w;
    A0.w += __uint_as_float(v.y & 0xffff0000u) * w;
    A1.x += __uint_as_float(v.z << 16) * w;
    A1.y += __uint_as_float(v.z & 0xffff0000u) * w;
    A1.z += __uint_as_float(v.w << 16) * w;
    A1.w += __uint_as_float(v.w & 0xffff0000u) * w;
}
__device__ __forceinline__ void acc8(float4& A0, float4& A1, uint4 v) {
    A0.x += __uint_as_float(v.x << 16);
    A0.y += __uint_as_float(v.x & 0xffff0000u);
    A0.z += __uint_as_float(v.y << 16);
    A0.w += __uint_as_float(v.y & 0xffff0000u);
    A1.x += __uint_as_float(v.z << 16);
    A1.y += __uint_as_float(v.z & 0xffff0000u);
    A1.z += __uint_as_float(v.w << 16);
    A1.w += __uint_as_float(v.w & 0xffff0000u);
}

// ---------------- W staging: f32 LDS tile ----------------
__device__ __forceinline__ void stage_W(const float* __restrict__ W, float* sW) {
    int t = threadIdx.x;
    const float4* W4 = (const float4*)W;
    float4* sW4 = (float4*)sW;
#pragma unroll
    for (int i = 0; i < 4; i++) sW4[t + NTHREADS * i] = W4[t + NTHREADS * i];
}

// ---------------- GEMM compute phase: acc over sX (f32) x sW (f32) ----------------
__device__ __forceinline__ void gemm_compute(
    const float* __restrict__ sW, const float* __restrict__ sX,
    const float* __restrict__ sD, __hip_bfloat16* __restrict__ out,
    int n_rows, int row_base) {
    int t = threadIdx.x;
    int c = t & 63;
    int r0 = t >> 6;
    float acc[16];
#pragma unroll
    for (int j = 0; j < 16; j++) acc[j] = 0.f;

    for (int k = 0; k < 64; k += 4) {
        float w0 = sW[(k + 0) * 64 + c];
        float w1 = sW[(k + 1) * 64 + c];
        float w2 = sW[(k + 2) * 64 + c];
        float w3 = sW[(k + 3) * 64 + c];
#pragma unroll
        for (int j = 0; j < 16; j++) {
            float4 xv = *(const float4*)(sX + (r0 + 4 * j) * 64 + k);
            acc[j] += xv.x * w0 + xv.y * w1 + xv.z * w2 + xv.w * w3;
        }
    }

#pragma unroll
    for (int j = 0; j < 16; j++) {
        int r = row_base + r0 + 4 * j;
        if (r < n_rows) {
            float s = sD ? sD[r0 + 4 * j] : 1.0f;
            out[(size_t)r * 64 + c] = __float2bfloat16(s * acc[j]);
        }
    }
}

// ---------------- pass1 (edge partition scatter) fused with layer-0 GEMM ----------------
__global__ __launch_bounds__(NTHREADS) void pass1_gemm0(
    const int* __restrict__ ei, int nE, int* gcur, uint32* __restrict__ pbuf, int npart,
    const float* __restrict__ x, __hip_bfloat16* __restrict__ U,
    const float* __restrict__ W, int n_rows, int nP1) {
    __shared__ __align__(16) float sW[64 * 64];
    __shared__ __align__(16) float sX[64 * 64];

    int bid = blockIdx.x;
    int t = threadIdx.x;

    if (bid < nP1) {
        int* hist = (int*)sW;            // [npart]
        int* base = hist + npart;        // [npart]
        int* cnt  = base + npart;        // [npart]
        for (int i = t; i < npart; i += NTHREADS) { hist[i] = 0; cnt[i] = 0; }
        __syncthreads();

        int e0 = bid * P1_EDGES;
#pragma unroll 4
        for (int j = 0; j < P1_EDGES / NTHREADS; j++) {
            int e = e0 + j * NTHREADS + t;
            if (e < nE) atomicAdd(&hist[ei[nE + e] >> 8], 1);
        }
        __syncthreads();
        for (int i = t; i < npart; i += NTHREADS) {
            base[i] = hist[i] ? atomicAdd(&gcur[i * 16], hist[i]) : 0;
        }
        __syncthreads();
#pragma unroll 4
        for (int j = 0; j < P1_EDGES / NTHREADS; j++) {
            int e = e0 + j * NTHREADS + t;
            if (e < nE) {
                int s = ei[e];
                int d = ei[nE + e];
                int p = d >> 8;
                int off = atomicAdd(&cnt[p], 1);
                int pos = base[p] + off;
                if (pos < CAP) pbuf[(size_t)p * CAP + pos] = ((uint32)s << 8) | (uint32)(d & 255);
            }
        }
        return;
    }

    int row_base = (bid - nP1) * 64;
    stage_W(W, sW);
    float4* sX4 = (float4*)sX;
#pragma unroll
    for (int i = 0; i < 4; i++) {
        int idx = t + NTHREADS * i;
        int r = row_base + (idx >> 4);
        float4 v = make_float4(0.f, 0.f, 0.f, 0.f);
        if (r < n_rows) v = ((const float4*)(x + (size_t)r * 64))[idx & 15];
        sX4[idx] = v;
    }
    __syncthreads();
    gemm_compute(sW, sX, nullptr, U, n_rows, row_base);
}

// ---------------- scan over partition totals -> pbase (exclusive); row_ptr[N]=E ----------------
__global__ __launch_bounds__(512) void scanP(const int* __restrict__ gcur, int* pbase,
                                             int npart, int n, int nE, int* row_ptr) {
    __shared__ int sm[512];
    int t = threadIdx.x;
    int v = (t < npart) ? gcur[t * 16] : 0;
    sm[t] = v;
    __syncthreads();
    for (int off = 1; off < 512; off <<= 1) {
        int a = (t >= off) ? sm[t - off] : 0;
        __syncthreads();
        sm[t] += a;
        __syncthreads();
    }
    if (t < npart) pbase[t] = sm[t] - v;
    if (t == 0) row_ptr[n] = nE;
}

// ---------------- pass2: per-partition CSR finish ----------------
__global__ __launch_bounds__(NTHREADS) void pass2(
    const uint32* __restrict__ pbuf, const int* __restrict__ gcur,
    const int* __restrict__ pbase, int* __restrict__ row_ptr,
    float* __restrict__ dis, int* __restrict__ col, int n) {
    __shared__ int hist[256];
    __shared__ int excl[256];
    __shared__ int cnt[256];
    __shared__ int sm[256];

    int p = blockIdx.x;
    int t = threadIdx.x;
    hist[t] = 0;
    cnt[t] = 0;
    __syncthreads();

    int total = gcur[p * 16];
    if (total > CAP) total = CAP;
    const uint32* pb = pbuf + (size_t)p * CAP;

    for (int i = t; i < total; i += NTHREADS) atomicAdd(&hist[pb[i] & 255], 1);
    __syncthreads();

    sm[t] = hist[t];
    __syncthreads();
    for (int off = 1; off < 256; off <<= 1) {
        int a = (t >= off) ? sm[t - off] : 0;
        __syncthreads();
        sm[t] += a;
        __syncthreads();
    }
    excl[t] = sm[t] - hist[t];
    __syncthreads();

    int rbase = pbase[p];
    int node = p * 256 + t;
    if (node < n) {
        row_ptr[node] = rbase + excl[t];
        dis[node] = rsqrtf(1.0f + (float)hist[t]);
    }

    for (int i = t; i < total; i += NTHREADS) {
        uint32 v = pb[i];
        int dl = v & 255;
        int off = atomicAdd(&cnt[dl], 1);
        col[rbase + excl[dl] + off] = (int)(v >> 8);
    }
}

// ---------------- gather one node's aggregated+activated row into LDS ----------------
template <bool WEIGHTED>
__device__ __forceinline__ void gather_row(
    const uint4* __restrict__ T8, const float* __restrict__ dis,
    const float* __restrict__ bias,
    const int* __restrict__ row_ptr, const int* __restrict__ col,
    int node, int q, float* __restrict__ sXrow, int n) {
    float4 o0, o1;
    if (node < n) {
        float dn = dis[node];
        float4 a0 = make_float4(0.f, 0.f, 0.f, 0.f);
        float4 a1 = make_float4(0.f, 0.f, 0.f, 0.f);
        {
            uint4 sv = T8[(size_t)node * 8 + q];
            if (WEIGHTED) fma8(a0, a1, sv, dn);
            else          acc8(a0, a1, sv);
        }
        int e0 = row_ptr[node];
        int e1 = row_ptr[node + 1];
        int e = e0;
        for (; e + 7 < e1; e += 8) {
            int s0 = col[e],     s1 = col[e + 1], s2 = col[e + 2], s3 = col[e + 3];
            int s4 = col[e + 4], s5 = col[e + 5], s6 = col[e + 6], s7 = col[e + 7];
            uint4 v0 = T8[(size_t)s0 * 8 + q];
            uint4 v1 = T8[(size_t)s1 * 8 + q];
            uint4 v2 = T8[(size_t)s2 * 8 + q];
            uint4 v3 = T8[(size_t)s3 * 8 + q];
            uint4 v4 = T8[(size_t)s4 * 8 + q];
            uint4 v5 = T8[(size_t)s5 * 8 + q];
            uint4 v6 = T8[(size_t)s6 * 8 + q];
            uint4 v7 = T8[(size_t)s7 * 8 + q];
            if (WEIGHTED) {
                fma8(a0, a1, v0, dis[s0]); fma8(a0, a1, v1, dis[s1]);
                fma8(a0, a1, v2, dis[s2]); fma8(a0, a1, v3, dis[s3]);
                fma8(a0, a1, v4, dis[s4]); fma8(a0, a1, v5, dis[s5]);
                fma8(a0, a1, v6, dis[s6]); fma8(a0, a1, v7, dis[s7]);
            } else {
                acc8(a0, a1, v0); acc8(a0, a1, v1); acc8(a0, a1, v2); acc8(a0, a1, v3);
                acc8(a0, a1, v4); acc8(a0, a1, v5); acc8(a0, a1, v6); acc8(a0, a1, v7);
            }
        }
        for (; e + 3 < e1; e += 4) {
            int s0 = col[e], s1 = col[e + 1], s2 = col[e + 2], s3 = col[e + 3];
            uint4 v0 = T8[(size_t)s0 * 8 + q];
            uint4 v1 = T8[(size_t)s1 * 8 + q];
            uint4 v2 = T8[(size_t)s2 * 8 + q];
            uint4 v3 = T8[(size_t)s3 * 8 + q];
            if (WEIGHTED) {
                fma8(a0, a1, v0, dis[s0]); fma8(a0, a1, v1, dis[s1]);
                fma8(a0, a1, v2, dis[s2]); fma8(a0, a1, v3, dis[s3]);
            } else {
                acc8(a0, a1, v0); acc8(a0, a1, v1); acc8(a0, a1, v2); acc8(a0, a1, v3);
            }
        }
        for (; e < e1; e++) {
            int s0 = col[e];
            uint4 v0 = T8[(size_t)s0 * 8 + q];
            if (WEIGHTED) fma8(a0, a1, v0, dis[s0]);
            else          acc8(a0, a1, v0);
        }
        float4 b0 = ((const float4*)bias)[q * 2];
        float4 b1 = ((const float4*)bias)[q * 2 + 1];
        o0.x = fmaxf(b0.x + dn * a0.x, 0.f);
        o0.y = fmaxf(b0.y + dn * a0.y, 0.f);
        o0.z = fmaxf(b0.z + dn * a0.z, 0.f);
        o0.w = fmaxf(b0.w + dn * a0.w, 0.f);
        o1.x = fmaxf(b1.x + dn * a1.x, 0.f);
        o1.y = fmaxf(b1.y + dn * a1.y, 0.f);
        o1.z = fmaxf(b1.z + dn * a1.z, 0.f);
        o1.w = fmaxf(b1.w + dn * a1.w, 0.f);
    } else {
        o0 = make_float4(0.f, 0.f, 0.f, 0.f);
        o1 = o0;
    }
    ((float4*)sXrow)[q * 2] = o0;
    ((float4*)sXrow)[q * 2 + 1] = o1;
}

// ---------------- fused aggregate(layer l) + GEMM(layer l+1) ----------------
template <bool WEIGHTED>
__global__ __launch_bounds__(NTHREADS) void agg_gemm(
    const __hip_bfloat16* __restrict__ Tin, __hip_bfloat16* __restrict__ Tout,
    const float* __restrict__ W, const float* __restrict__ dis,
    const float* __restrict__ bias,
    const int* __restrict__ row_ptr, const int* __restrict__ col, int n) {
    __shared__ __align__(16) float sW[64 * 64];
    __shared__ __align__(16) float sX[64 * 64];
    __shared__ float sD[64];
    int t = threadIdx.x;
    int row_base = blockIdx.x * 64;

    stage_W(W, sW);
    if (t < 64) {
        int r = row_base + t;
        sD[t] = (r < n) ? dis[r] : 0.f;
    }

    const uint4* T8 = (const uint4*)Tin;
    int q = t & 7;
    int l = t >> 3;  // 0..31
    gather_row<WEIGHTED>(T8, dis, bias, row_ptr, col, row_base + l,      q, sX + l * 64,        n);
    gather_row<WEIGHTED>(T8, dis, bias, row_ptr, col, row_base + 32 + l, q, sX + (32 + l) * 64, n);
    __syncthreads();

    gemm_compute(sW, sX, sD, Tout, n, row_base);
}

// ---------------- fused aggregate(layer 2) + sum-pool ----------------
__global__ __launch_bounds__(NTHREADS) void agg_pool(
    const __hip_bfloat16* __restrict__ Tin,
    const float* __restrict__ dis, const float* __restrict__ bias,
    const int* __restrict__ row_ptr, const int* __restrict__ col,
    const int* __restrict__ gid, float* __restrict__ pooled, int n) {
    __shared__ __align__(16) float sX[64 * 64];
    __shared__ int sG[64];
    int t = threadIdx.x;
    int row_base = blockIdx.x * 64;

    if (t < 64) {
        int r = row_base + t;
        sG[t] = (r < n) ? gid[r] : -1;
    }

    const uint4* T8 = (const uint4*)Tin;
    int q = t & 7;
    int l = t >> 3;
    gather_row<false>(T8, dis, bias, row_ptr, col, row_base + l,      q, sX + l * 64,        n);
    gather_row<false>(T8, dis, bias, row_ptr, col, row_base + 32 + l, q, sX + (32 + l) * 64, n);
    __syncthreads();

    int f = t & 63;
    int w = t >> 6;
    float racc = 0.f;
    int cur = -1;
#pragma unroll
    for (int i = 0; i < 16; i++) {
        int r = i * 4 + w;
        int g = sG[r];
        if (g != cur) {
            if (cur >= 0 && racc != 0.f) atomicAdd(&pooled[cur * 64 + f], racc);
            racc = 0.f;
            cur = g;
        }
        if (g >= 0) racc += sX[r * 64 + f];
    }
    if (cur >= 0 && racc != 0.f) atomicAdd(&pooled[cur * 64 + f], racc);
}

// ---------------- head MLP: one wave per graph (64 blocks x 64 threads) ----------------
__global__ __launch_bounds__(64) void head_kernel(
    const float* __restrict__ pooled, const float* __restrict__ gf,
    const float* __restrict__ glob_w, const float* __restrict__ glob_b,
    const float* __restrict__ lin1_w, const float* __restrict__ lin1_b,
    const float* __restrict__ lin2_w, const float* __restrict__ lin2_b,
    const float* __restrict__ lin3_w, const float* __restrict__ lin3_b,
    const float* __restrict__ lin4_w, const float* __restrict__ lin4_b,
    float* __restrict__ out) {
    __shared__ float pz[64];
    __shared__ float sgx[32];
    __shared__ float z1[64];
    __shared__ float z2[64];
    __shared__ float z3[64];
    int g = blockIdx.x;
    int t = threadIdx.x;

    pz[t] = pooled[g * 64 + t];
    if (t < 32) {
        float acc = glob_b[t];
        for (int k = 0; k < 32; k++) acc += gf[g * 32 + k] * glob_w[k * 32 + t];
        sgx[t] = fmaxf(acc, 0.f);
    }
    __syncthreads();

    {
        float acc = lin1_b[t];
        for (int k = 0; k < 64; k++) acc += pz[k] * lin1_w[k * 64 + t];
        z1[t] = fmaxf(acc, 0.f);
    }
    __syncthreads();
    {
        float acc = lin2_b[t];
        for (int k = 0; k < 64; k++) acc += z1[k] * lin2_w[k * 64 + t];
        for (int k = 0; k < 32; k++) acc += sgx[k] * lin2_w[(64 + k) * 64 + t];
        z2[t] = fmaxf(acc, 0.f);
    }
    __syncthreads();
    {
        float acc = lin3_b[t];
        for (int k = 0; k < 64; k++) acc += z2[k] * lin3_w[k * 64 + t];
        z3[t] = fmaxf(acc, 0.f);
    }
    __syncthreads();
    // out[g] = z3 . lin4_w + b  (keep k-ascending order: serial on lane 0 over LDS)
    if (t == 0) {
        float acc = lin4_b[0];
        for (int k = 0; k < 64; k++) acc += z3[k] * lin4_w[k];
        out[g] = acc;
    }
}

extern "C" void kernel_launch(void* const* d_in, const int* in_sizes, int n_in,
                              void* d_out, int out_size, void* d_ws, size_t ws_size,
                              hipStream_t stream) {
    const float* x      = (const float*)d_in[0];
    const float* gf     = (const float*)d_in[1];
    const float* conv_w[3] = {(const float*)d_in[2], (const float*)d_in[4], (const float*)d_in[6]};
    const float* conv_b[3] = {(const float*)d_in[3], (const float*)d_in[5], (const float*)d_in[7]};
    const float* lin1_w = (const float*)d_in[8];
    const float* lin1_b = (const float*)d_in[9];
    const float* glob_w = (const float*)d_in[10];
    const float* glob_b = (const float*)d_in[11];
    const float* lin2_w = (const float*)d_in[12];
    const float* lin2_b = (const float*)d_in[13];
    const float* lin3_w = (const float*)d_in[14];
    const float* lin3_b = (const float*)d_in[15];
    const float* lin4_w = (const float*)d_in[16];
    const float* lin4_b = (const float*)d_in[17];
    const int* ei  = (const int*)d_in[18];
    const int* gid = (const int*)d_in[19];

    const int N = in_sizes[0] / 64;   // 100000
    const int E = in_sizes[18] / 2;   // 1600000
    const int NPART = (N + 255) >> 8; // 391
    const int G = 64;

    // workspace layout (16B-aligned segments)
    char* ws = (char*)d_ws;
    float* dis     = (float*)ws;                 ws += (size_t)N * 4;
    float* pooled  = (float*)ws;                 ws += 4096 * 4;
    __hip_bfloat16* U  = (__hip_bfloat16*)ws;    ws += (size_t)N * 64 * 2;  // layer0 out / layer2 in
    __hip_bfloat16* T1 = (__hip_bfloat16*)ws;    ws += (size_t)N * 64 * 2;  // layer1 out
    int*   row_ptr = (int*)ws;                   ws += ((size_t)N + 4) * 4;
    int*   col     = (int*)ws;                   ws += (size_t)E * 4;
    uint32* pbuf   = (uint32*)ws;                ws += (size_t)NPART * CAP * 4;
    int*   gcur    = (int*)ws;                   ws += (size_t)NPART * 16 * 4;
    int*   pbase   = (int*)ws;                   ws += (size_t)((NPART + 15) & ~15) * 4;

    const int nP1 = (E + P1_EDGES - 1) / P1_EDGES;   // 196
    const int gemm_blocks = (N + 63) / 64;           // 1563

    // ---- CSR build pass1 (partition scatter) fused with unscaled layer-0 GEMM ----
    hipMemsetAsync(gcur, 0, (size_t)NPART * 16 * 4, stream);
    hipMemsetAsync(pooled, 0, 4096 * 4, stream);
    pass1_gemm0<<<nP1 + gemm_blocks, NTHREADS, 0, stream>>>(
        ei, E, gcur, pbuf, NPART, x, U, conv_w[0], N, nP1);

    // ---- partition-total scan + per-partition CSR finish ----
    scanP<<<1, 512, 0, stream>>>(gcur, pbase, NPART, N, E, row_ptr);
    pass2<<<NPART, NTHREADS, 0, stream>>>(pbuf, gcur, pbase, row_ptr, dis, col, N);

    // agg(layer0, weighted) + gemm(layer1): U -> T1 (prescaled)
    agg_gemm<true><<<gemm_blocks, NTHREADS, 0, stream>>>(
        U, T1, conv_w[1], dis, conv_b[0], row_ptr, col, N);

    // agg(layer1) + gemm(layer2): T1 -> U (prescaled, reused buffer)
    agg_gemm<false><<<gemm_blocks, NTHREADS, 0, stream>>>(
        T1, U, conv_w[2], dis, conv_b[1], row_ptr, col, N);

    // agg(layer2) + relu + pool: U -> pooled
    agg_pool<<<gemm_blocks, NTHREADS, 0, stream>>>(
        U, dis, conv_b[2], row_ptr, col, gid, pooled, N);

    // head MLP: one wave per graph
    head_kernel<<<G, 64, 0, stream>>>(pooled, gf,
                                      glob_w, glob_b, lin1_w, lin1_b,
                                      lin2_w, lin2_b, lin3_w, lin3_b,
                                      lin4_w, lin4_b, (float*)d_out);
}